// Round 21
// baseline (480.056 us; speedup 1.0000x reference)
//
#include <hip/hip_runtime.h>
#include <math.h>
#include <stdint.h>

typedef _Float16 f16;
typedef _Float16 f16x8 __attribute__((ext_vector_type(8)));
typedef float f32x4 __attribute__((ext_vector_type(4)));
typedef unsigned short u16;
typedef u16 u16x8 __attribute__((ext_vector_type(8)));

#define HID 256
#define NS1C 100              // layer-1 conv K-steps: 25 taps x 4 channel-groups
#define NS2 8                 // 256/32
#define NPX 65536
#define BPXG 256              // pixels per block (one full image row)
#define NBG (NPX/BPXG)        // 256 blocks -> 1 round at 1 block/CU
#define SPAD 260
#define NSP (SPAD*SPAD)

// ws layout (bytes) — ~106 MB, fits (proven r9)
#define OFF_W1C 0
#define SZ_W1C  ((size_t)NS1C*32768)
#define OFF_W2  SZ_W1C
#define SZ_W2   ((size_t)NS2*32768)
#define OFF_W3  (OFF_W2+SZ_W2)
#define OFF_XH  ((size_t)4194304)
#define SZ_XP   ((size_t)NSP*128*2)
#define OFF_XL  (OFF_XH + SZ_XP)
#define OFF_HH  (OFF_XL + SZ_XP)
#define SZ_HP   ((size_t)NPX*HID*2)
#define OFF_HL  (OFF_HH + SZ_HP)

// tap offsets: dy*SPAD + dx for tap = dy*5+dx
__device__ static const int TAPOFF25[25] = {
  0*SPAD+0, 0*SPAD+1, 0*SPAD+2, 0*SPAD+3, 0*SPAD+4,
  1*SPAD+0, 1*SPAD+1, 1*SPAD+2, 1*SPAD+3, 1*SPAD+4,
  2*SPAD+0, 2*SPAD+1, 2*SPAD+2, 2*SPAD+3, 2*SPAD+4,
  3*SPAD+0, 3*SPAD+1, 3*SPAD+2, 3*SPAD+3, 3*SPAD+4,
  4*SPAD+0, 4*SPAD+1, 4*SPAD+2, 4*SPAD+3, 4*SPAD+4
};

__device__ inline void split2(float v, u16& h, u16& l){
  f16 hv = (f16)v;
  f16 lv = (f16)(v - (float)hv);
  h = __builtin_bit_cast(u16, hv);
  l = __builtin_bit_cast(u16, lv);
}

// ---------------------------------------------------------------------------
// prep bodies (proven layouts, unchanged math), fused into one launch
// ---------------------------------------------------------------------------
__device__ inline void prep_w_body(const float* __restrict__ W, int Kact,
                                   u16* __restrict__ outp, int t){
  int s = t >> 10, r = t & 1023;
  int w = r >> 8, nf = (r >> 6) & 3, l = r & 63;
  int col = w*64 + nf*16 + (l & 15);
  int kb  = s*32 + (l >> 4)*8;
  u16x8 hv, lv;
  #pragma unroll
  for (int j = 0; j < 8; ++j){
    int k = kb + j;
    float v = (k < Kact) ? W[(size_t)k*HID + col] : 0.f;
    u16 h, lo; split2(v, h, lo);
    hv[j] = h; lv[j] = lo;
  }
  size_t U0 = ((((size_t)s*4 + w)*4 + nf)*2 + 0)*64 + l;
  *(u16x8*)(outp + U0*8)      = hv;
  *(u16x8*)(outp + (U0+64)*8) = lv;
}

__device__ inline void prep_w1c_body(const float* __restrict__ W1,
                                     u16* __restrict__ outp, int t){
  int s = t >> 10, r = t & 1023;
  int w = r >> 8, nf = (r >> 6) & 3, l = r & 63;
  int col = w*64 + nf*16 + (l & 15);
  int tap = s >> 2, cg = s & 3;
  int cb  = cg*32 + (l >> 4)*8;
  u16x8 hv, lv;
  #pragma unroll
  for (int j = 0; j < 8; ++j){
    int c = cb + j;
    float v = W1[(size_t)(c*25 + tap)*HID + col];
    u16 h, lo; split2(v, h, lo);
    hv[j] = h; lv[j] = lo;
  }
  size_t U0 = ((((size_t)s*4 + w)*4 + nf)*2 + 0)*64 + l;
  *(u16x8*)(outp + U0*8)      = hv;
  *(u16x8*)(outp + (U0+64)*8) = lv;
}

__device__ inline void prep_x_body(const float* __restrict__ xi,
                                   u16* __restrict__ Xh, u16* __restrict__ Xl,
                                   int sp){
  if (sp >= NSP) return;
  int py = sp / SPAD;
  int px = sp - py*SPAD;
  bool inb = (py >= 2) & (py < 258) & (px >= 2) & (px < 258);
  const float* xin = xi + ((size_t)(py-2)<<8) + (px-2);
  #pragma unroll 4
  for (int cg = 0; cg < 16; ++cg){
    u16x8 hv, lv;
    #pragma unroll
    for (int j = 0; j < 8; ++j){
      float v = inb ? xin[((size_t)(cg*8 + j))<<16] : 0.f;
      u16 h, l; split2(v, h, l); hv[j] = h; lv[j] = l;
    }
    *(u16x8*)(Xh + (size_t)sp*128 + cg*8) = hv;
    *(u16x8*)(Xl + (size_t)sp*128 + cg*8) = lv;
  }
}

// blocks [0,400) W1 tap-major; [400,432) W2; [432,464) W3; [464,729) X planes
__global__ __launch_bounds__(256)
void prep_all(const float* __restrict__ xi, const float* __restrict__ W1,
              const float* __restrict__ W2, const float* __restrict__ W3,
              u16* __restrict__ W1c, u16* __restrict__ W2p, u16* __restrict__ W3p,
              u16* __restrict__ Xh, u16* __restrict__ Xl){
  int bid = blockIdx.x, tid = threadIdx.x;
  if (bid < 400){
    prep_w1c_body(W1, W1c, bid*256 + tid);
  } else if (bid < 432){
    prep_w_body(W2, HID, W2p, (bid-400)*256 + tid);
  } else if (bid < 464){
    prep_w_body(W3, HID, W3p, (bid-432)*256 + tid);
  } else {
    prep_x_body(xi, Xh, Xl, (bid-464)*256 + tid);
  }
}

// ---------------------------------------------------------------------------
// 256px x 256col GEMM, 512 thr = 8 waves (wave = 128px x 64col, 96 MFMA/step).
// Counted-vmcnt pipeline (one vmcnt(0)+barrier per step), TERM-MAJOR MFMA,
// and now the m201-style PER-PHASE BARRIER RHYTHM: 6 phases of 16 MFMA, each
//   {phase reads (+staging chunk) -> s_barrier -> lgkmcnt(0) -> setprio(1)
//    -> 16 MFMA -> setprio(0) -> s_barrier}.
// Buffer lifetimes and vmcnt discipline identical to r20; per-acc term order
// (hh->lh->hl) unchanged => bitwise-identical output.
// MODE 0: A = conv taps of Xh/Xl, nt=100, exact-f32 coords in epilogue.
// MODE 1: A = Hh/Hl, nt=8. MODE 2: + fused layer-4 tail.
// ---------------------------------------------------------------------------
template<int MODE>
__global__ __launch_bounds__(512, 2)
void gemm(const u16* __restrict__ Ah, const u16* __restrict__ Al,
          const u16* __restrict__ Wp, const float* __restrict__ W1,
          const float* __restrict__ bias, u16* __restrict__ Hh, u16* __restrict__ Hl,
          const float* __restrict__ W4, const float* __restrict__ b4,
          float* __restrict__ out, int nt)
{
  __shared__ __align__(16) u16 Sb[65536];   // 128 KB pool: A@{0,32K}, B@{64K,96K}

  const int tid  = threadIdx.x;
  const int lane = tid & 63;
  const int wv   = tid >> 6;            // 0..7
  const int wm   = wv >> 2, wn = wv & 3;

  int bid = blockIdx.x;
  bid = (bid & 7)*(NBG/8) + (bid >> 3);   // XCD-chunked swizzle (256%8==0)
  const int pxb = bid * BPXG;
  const int y   = bid;

  // hoisted staging-address invariants
  const int alane  = (lane & 15);
  const int akoff  = (lane >> 4)*8;
  const size_t abase0 = MODE == 0
      ? ((size_t)(y*SPAD + wv*32 + alane)*128 + akoff)
      : ((size_t)(pxb + wv*32 + alane)*HID + akoff);
  const size_t abaseStride = MODE == 0 ? (size_t)16*128 : (size_t)16*HID;

  f32x4 acc[8][4];
  #pragma unroll
  for (int a=0;a<8;a++)
    #pragma unroll
    for (int bq=0;bq<4;bq++) acc[a][bq] = f32x4{0.f,0.f,0.f,0.f};

#define A_STAGE(S, BUF) do { \
    size_t soff; \
    if (MODE == 0){ \
      const int tap = (S) >> 2, cg = (S) & 3; \
      soff = abase0 + (size_t)TAPOFF25[tap]*128 + cg*32; \
    } else { \
      soff = abase0 + (size_t)(S)*32; \
    } \
    _Pragma("unroll") \
    for (int u=0;u<2;++u){ \
      const int mfb = wv*2 + u; \
      const size_t off = soff + (size_t)u*abaseStride; \
      __builtin_amdgcn_global_load_lds( \
        (const __attribute__((address_space(1))) uint32_t*)(Ah + off), \
        (__attribute__((address_space(3))) uint32_t*)((char*)Sb + (size_t)(BUF)*32768 + (mfb*2+0)*1024), \
        16, 0, 0); \
      __builtin_amdgcn_global_load_lds( \
        (const __attribute__((address_space(1))) uint32_t*)(Al + off), \
        (__attribute__((address_space(3))) uint32_t*)((char*)Sb + (size_t)(BUF)*32768 + (mfb*2+1)*1024), \
        16, 0, 0); \
    } \
  } while(0)

#define B_STAGE(S, BUF) do { \
    const char* _src = (const char*)Wp + (size_t)(S)*32768 + wv*4096 + lane*16; \
    char* _dst = (char*)Sb + 65536 + (size_t)(BUF)*32768 + wv*4096; \
    _Pragma("unroll") \
    for (int i=0;i<4;++i) \
      __builtin_amdgcn_global_load_lds( \
        (const __attribute__((address_space(1))) uint32_t*)(_src + i*1024), \
        (__attribute__((address_space(3))) uint32_t*)(_dst + i*1024), 16, 0, 0); \
  } while(0)

// one MFMA cluster of 16 (4 m x 4 nf) accumulating into acc[BASE+m][nf]
#define CLUSTER(AV, BV, BASE) do { \
    __builtin_amdgcn_s_setprio(1); \
    _Pragma("unroll") \
    for (int m=0;m<4;++m) \
      _Pragma("unroll") \
      for (int nf=0;nf<4;++nf) \
        acc[(BASE)+m][nf] = __builtin_amdgcn_mfma_f32_16x16x32_f16(AV[m], BV[nf], acc[(BASE)+m][nf], 0,0,0); \
    __builtin_amdgcn_s_setprio(0); \
  } while(0)

#define PHASE_BAR() do { \
    __builtin_amdgcn_sched_barrier(0); \
    __builtin_amdgcn_s_barrier(); \
    asm volatile("s_waitcnt lgkmcnt(0)" ::: "memory"); \
    __builtin_amdgcn_sched_barrier(0); \
  } while(0)

#define POST_BAR() do { \
    __builtin_amdgcn_sched_barrier(0); \
    __builtin_amdgcn_s_barrier(); \
    __builtin_amdgcn_sched_barrier(0); \
  } while(0)

  A_STAGE(0, 0); B_STAGE(0, 0);

  for (int t = 0; t < nt; ++t){
    asm volatile("s_waitcnt vmcnt(0)" ::: "memory");
    __builtin_amdgcn_s_barrier();          // step barrier: buf staged, prev reads done
    __builtin_amdgcn_sched_barrier(0);
    const int cur = t & 1;

    const u16* Abuf = (const u16*)Sb + (size_t)cur*16384;
    const u16* Bbuf = (const u16*)Sb + 32768 + (size_t)cur*16384;

    // ---- phase 1: reads {bh, a0h} + A staging issue | C1 = a0h x bh
    f16x8 bh[4], a0h[4];
    #pragma unroll
    for (int nf=0;nf<4;++nf)
      bh[nf] = *(const f16x8*)(Bbuf + ((size_t)((wn*4+nf)*2+0)*64 + lane)*8);
    #pragma unroll
    for (int m=0;m<4;++m)
      a0h[m] = *(const f16x8*)(Abuf + ((size_t)((wm*8+m)*2+0)*64 + lane)*8);
    if (t+1 < nt) A_STAGE(t+1, cur^1);
    PHASE_BAR();
    CLUSTER(a0h, bh, 0);
    POST_BAR();

    // ---- phase 2: reads {a0l} + B staging issue | C2 = a0l x bh
    f16x8 a0l[4];
    #pragma unroll
    for (int m=0;m<4;++m)
      a0l[m] = *(const f16x8*)(Abuf + ((size_t)((wm*8+m)*2+1)*64 + lane)*8);
    if (t+1 < nt) B_STAGE(t+1, cur^1);
    PHASE_BAR();
    CLUSTER(a0l, bh, 0);
    POST_BAR();

    // ---- phase 3: reads {bl} | C3 = a0h x bl
    f16x8 bl[4];
    #pragma unroll
    for (int nf=0;nf<4;++nf)
      bl[nf] = *(const f16x8*)(Bbuf + ((size_t)((wn*4+nf)*2+1)*64 + lane)*8);
    PHASE_BAR();
    CLUSTER(a0h, bl, 0);
    POST_BAR();

    // ---- phase 4: reads {a1h} | C4 = a1h x bh
    f16x8 a1h[4];
    #pragma unroll
    for (int m=0;m<4;++m)
      a1h[m] = *(const f16x8*)(Abuf + ((size_t)((wm*8+4+m)*2+0)*64 + lane)*8);
    PHASE_BAR();
    CLUSTER(a1h, bh, 4);
    POST_BAR();

    // ---- phase 5: reads {a1l} | C5 = a1l x bh
    f16x8 a1l[4];
    #pragma unroll
    for (int m=0;m<4;++m)
      a1l[m] = *(const f16x8*)(Abuf + ((size_t)((wm*8+4+m)*2+1)*64 + lane)*8);
    PHASE_BAR();
    CLUSTER(a1l, bh, 4);
    POST_BAR();

    // ---- phase 6: no reads | C6 = a1h x bl (runs into step-end barrier)
    CLUSTER(a1h, bl, 4);
  }

  __syncthreads();   // loop LDS dead; MODE 2 overlays Sb

  float bcol[4];
  #pragma unroll
  for (int nf=0;nf<4;++nf) bcol[nf] = bias[wn*64 + nf*16 + (lane&15)];

  if (MODE == 0){
    float wyv[4], wxv[4];
    #pragma unroll
    for (int nf=0;nf<4;++nf){
      int col = wn*64 + nf*16 + (lane&15);
      wyv[nf] = W1[(size_t)3200*HID + col];
      wxv[nf] = W1[(size_t)3201*HID + col];
    }
    const float gy = -1.f + (2.f/255.f)*(float)y;
    #pragma unroll
    for (int mf=0;mf<8;++mf)
      #pragma unroll
      for (int nf=0;nf<4;++nf)
        #pragma unroll
        for (int j=0;j<4;++j){
          int row = wm*128 + mf*16 + (lane>>4)*4 + j;          // 0..255 = x coord
          float gx = -1.f + (2.f/255.f)*(float)row;
          float z = acc[mf][nf][j] + bcol[nf] + gy*wyv[nf] + gx*wxv[nf];
          float h = sinf(30.f*z);
          u16 hh,ll; split2(h,hh,ll);
          int col = wn*64 + nf*16 + (lane&15);
          size_t o = (size_t)(pxb+row)*HID + col;
          Hh[o] = hh; Hl[o] = ll;
        }
  } else if (MODE == 1){
    #pragma unroll
    for (int mf=0;mf<8;++mf)
      #pragma unroll
      for (int nf=0;nf<4;++nf)
        #pragma unroll
        for (int j=0;j<4;++j){
          float z = acc[mf][nf][j] + bcol[nf];
          float h = sinf(30.f*z);
          u16 hh,ll; split2(h,hh,ll);
          int row = wm*128 + mf*16 + (lane>>4)*4 + j;
          int col = wn*64 + nf*16 + (lane&15);
          size_t o = (size_t)(pxb+row)*HID + col;
          Hh[o] = hh; Hl[o] = ll;
        }
  } else {
    float (*red)[BPXG][3] = (float(*)[BPXG][3])(void*)Sb;  // 24 KB overlay, bufs dead
    float w4v[4][3];
    #pragma unroll
    for (int nf=0;nf<4;++nf){
      int col = wn*64 + nf*16 + (lane&15);
      w4v[nf][0]=W4[col*3+0]; w4v[nf][1]=W4[col*3+1]; w4v[nf][2]=W4[col*3+2];
    }
    #pragma unroll
    for (int mf=0;mf<8;++mf)
      #pragma unroll
      for (int j=0;j<4;++j){
        float s0=0.f,s1=0.f,s2=0.f;
        #pragma unroll
        for (int nf=0;nf<4;++nf){
          float h = sinf(30.f*(acc[mf][nf][j] + bcol[nf]));
          s0 += h*w4v[nf][0]; s1 += h*w4v[nf][1]; s2 += h*w4v[nf][2];
        }
        #pragma unroll
        for (int m=1;m<16;m<<=1){
          s0 += __shfl_xor(s0, m);
          s1 += __shfl_xor(s1, m);
          s2 += __shfl_xor(s2, m);
        }
        if ((lane & 15) == 0){
          int row = wm*128 + mf*16 + (lane>>4)*4 + j;
          red[wn + wm*4][row][0]=s0; red[wn + wm*4][row][1]=s1; red[wn + wm*4][row][2]=s2;
        }
      }
    __syncthreads();
    for (int o = tid; o < BPXG*3; o += 512){
      int px = o & 255, c = o >> 8;
      int wb = (px >> 7)*4;    // waves with wm = px>>7 hold this row
      float v = red[wb+0][px][c]+red[wb+1][px][c]+red[wb+2][px][c]+red[wb+3][px][c] + b4[c];
      out[(size_t)c*NPX + pxb + px] = v;
    }
  }
#undef A_STAGE
#undef B_STAGE
#undef CLUSTER
#undef PHASE_BAR
#undef POST_BAR
}

// ---------------------------------------------------------------------------
extern "C" void kernel_launch(void* const* d_in, const int* in_sizes, int n_in,
                              void* d_out, int out_size, void* d_ws, size_t ws_size,
                              hipStream_t stream) {
  const float* xi = (const float*)d_in[0];
  const float* W1 = (const float*)d_in[1];
  const float* b1 = (const float*)d_in[2];
  const float* W2 = (const float*)d_in[3];
  const float* b2 = (const float*)d_in[4];
  const float* W3 = (const float*)d_in[5];
  const float* b3 = (const float*)d_in[6];
  const float* W4 = (const float*)d_in[7];
  const float* b4 = (const float*)d_in[8];
  float* out = (float*)d_out;

  char* ws = (char*)d_ws;
  u16* W1c = (u16*)(ws + OFF_W1C);
  u16* W2p = (u16*)(ws + OFF_W2);
  u16* W3p = (u16*)(ws + OFF_W3);
  u16* Xh  = (u16*)(ws + OFF_XH);
  u16* Xl  = (u16*)(ws + OFF_XL);
  u16* Hh  = (u16*)(ws + OFF_HH);
  u16* Hl  = (u16*)(ws + OFF_HL);

  // 400 (W1 tap-major) + 32 (W2) + 32 (W3) + 265 (X planes) = 729 blocks
  prep_all<<<729, 256, 0, stream>>>(xi, W1, W2, W3, W1c, W2p, W3p, Xh, Xl);

  dim3 grid(NBG), block(512);
  gemm<0><<<grid, block, 0, stream>>>(Xh, Xl, W1c, W1, b1, Hh, Hl,
                                      nullptr, nullptr, nullptr, NS1C);
  gemm<1><<<grid, block, 0, stream>>>(Hh, Hl, W2p, nullptr, b2, Hh, Hl,
                                      nullptr, nullptr, nullptr, NS2);
  gemm<2><<<grid, block, 0, stream>>>(Hh, Hl, W3p, nullptr, b3, nullptr, nullptr,
                                      W4, b4, out, NS2);
}

// Round 22
// 445.715 us; speedup vs baseline: 1.0770x; 1.0770x over previous
//
#include <hip/hip_runtime.h>
#include <math.h>
#include <stdint.h>

typedef _Float16 f16;
typedef _Float16 f16x8 __attribute__((ext_vector_type(8)));
typedef float f32x4 __attribute__((ext_vector_type(4)));
typedef unsigned short u16;
typedef u16 u16x8 __attribute__((ext_vector_type(8)));

#define HID 256
#define NS1C 100              // layer-1 conv K-steps: 25 taps x 4 channel-groups
#define NS2 8                 // 256/32
#define NPX 65536
#define BPXG 256              // pixels per block (one full image row)
#define NBG (NPX/BPXG)        // 256 blocks -> 1 round at 1 block/CU
#define SPAD 260
#define NSP (SPAD*SPAD)

// ws layout (bytes) — ~106 MB, fits (proven r9)
#define OFF_W1C 0
#define SZ_W1C  ((size_t)NS1C*32768)
#define OFF_W2  SZ_W1C
#define SZ_W2   ((size_t)NS2*32768)
#define OFF_W3  (OFF_W2+SZ_W2)
#define OFF_XH  ((size_t)4194304)
#define SZ_XP   ((size_t)NSP*128*2)
#define OFF_XL  (OFF_XH + SZ_XP)
#define OFF_HH  (OFF_XL + SZ_XP)
#define SZ_HP   ((size_t)NPX*HID*2)
#define OFF_HL  (OFF_HH + SZ_HP)

// tap offsets: dy*SPAD + dx for tap = dy*5+dx
__device__ static const int TAPOFF25[25] = {
  0*SPAD+0, 0*SPAD+1, 0*SPAD+2, 0*SPAD+3, 0*SPAD+4,
  1*SPAD+0, 1*SPAD+1, 1*SPAD+2, 1*SPAD+3, 1*SPAD+4,
  2*SPAD+0, 2*SPAD+1, 2*SPAD+2, 2*SPAD+3, 2*SPAD+4,
  3*SPAD+0, 3*SPAD+1, 3*SPAD+2, 3*SPAD+3, 3*SPAD+4,
  4*SPAD+0, 4*SPAD+1, 4*SPAD+2, 4*SPAD+3, 4*SPAD+4
};

__device__ inline void split2(float v, u16& h, u16& l){
  f16 hv = (f16)v;
  f16 lv = (f16)(v - (float)hv);
  h = __builtin_bit_cast(u16, hv);
  l = __builtin_bit_cast(u16, lv);
}

// ---------------------------------------------------------------------------
// prep bodies (proven layouts, unchanged math), fused into one launch
// ---------------------------------------------------------------------------
__device__ inline void prep_w_body(const float* __restrict__ W, int Kact,
                                   u16* __restrict__ outp, int t){
  int s = t >> 10, r = t & 1023;
  int w = r >> 8, nf = (r >> 6) & 3, l = r & 63;
  int col = w*64 + nf*16 + (l & 15);
  int kb  = s*32 + (l >> 4)*8;
  u16x8 hv, lv;
  #pragma unroll
  for (int j = 0; j < 8; ++j){
    int k = kb + j;
    float v = (k < Kact) ? W[(size_t)k*HID + col] : 0.f;
    u16 h, lo; split2(v, h, lo);
    hv[j] = h; lv[j] = lo;
  }
  size_t U0 = ((((size_t)s*4 + w)*4 + nf)*2 + 0)*64 + l;
  *(u16x8*)(outp + U0*8)      = hv;
  *(u16x8*)(outp + (U0+64)*8) = lv;
}

__device__ inline void prep_w1c_body(const float* __restrict__ W1,
                                     u16* __restrict__ outp, int t){
  int s = t >> 10, r = t & 1023;
  int w = r >> 8, nf = (r >> 6) & 3, l = r & 63;
  int col = w*64 + nf*16 + (l & 15);
  int tap = s >> 2, cg = s & 3;
  int cb  = cg*32 + (l >> 4)*8;
  u16x8 hv, lv;
  #pragma unroll
  for (int j = 0; j < 8; ++j){
    int c = cb + j;
    float v = W1[(size_t)(c*25 + tap)*HID + col];
    u16 h, lo; split2(v, h, lo);
    hv[j] = h; lv[j] = lo;
  }
  size_t U0 = ((((size_t)s*4 + w)*4 + nf)*2 + 0)*64 + l;
  *(u16x8*)(outp + U0*8)      = hv;
  *(u16x8*)(outp + (U0+64)*8) = lv;
}

__device__ inline void prep_x_body(const float* __restrict__ xi,
                                   u16* __restrict__ Xh, u16* __restrict__ Xl,
                                   int sp){
  if (sp >= NSP) return;
  int py = sp / SPAD;
  int px = sp - py*SPAD;
  bool inb = (py >= 2) & (py < 258) & (px >= 2) & (px < 258);
  const float* xin = xi + ((size_t)(py-2)<<8) + (px-2);
  #pragma unroll 4
  for (int cg = 0; cg < 16; ++cg){
    u16x8 hv, lv;
    #pragma unroll
    for (int j = 0; j < 8; ++j){
      float v = inb ? xin[((size_t)(cg*8 + j))<<16] : 0.f;
      u16 h, l; split2(v, h, l); hv[j] = h; lv[j] = l;
    }
    *(u16x8*)(Xh + (size_t)sp*128 + cg*8) = hv;
    *(u16x8*)(Xl + (size_t)sp*128 + cg*8) = lv;
  }
}

// blocks [0,400) W1 tap-major; [400,432) W2; [432,464) W3; [464,729) X planes
__global__ __launch_bounds__(256)
void prep_all(const float* __restrict__ xi, const float* __restrict__ W1,
              const float* __restrict__ W2, const float* __restrict__ W3,
              u16* __restrict__ W1c, u16* __restrict__ W2p, u16* __restrict__ W3p,
              u16* __restrict__ Xh, u16* __restrict__ Xl){
  int bid = blockIdx.x, tid = threadIdx.x;
  if (bid < 400){
    prep_w1c_body(W1, W1c, bid*256 + tid);
  } else if (bid < 432){
    prep_w_body(W2, HID, W2p, (bid-400)*256 + tid);
  } else if (bid < 464){
    prep_w_body(W3, HID, W3p, (bid-432)*256 + tid);
  } else {
    prep_x_body(xi, Xh, Xl, (bid-464)*256 + tid);
  }
}

// ---------------------------------------------------------------------------
// 256px x 256col GEMM, 512 thr = 8 waves (wave = 128px x 64col, 96 MFMA/step).
// One barrier/step, counted-vmcnt pipeline, TERM-MAJOR MFMA, staging issue
// and late A-reads interleaved into the MFMA cluster (r20-proven best).
// MODE 0: A = conv taps of Xh/Xl, nt=100, exact-f32 coords in epilogue.
// MODE 1: A = Hh/Hl, nt=8. MODE 2: + fused layer-4 tail.
// ---------------------------------------------------------------------------
template<int MODE>
__global__ __launch_bounds__(512, 2)
void gemm(const u16* __restrict__ Ah, const u16* __restrict__ Al,
          const u16* __restrict__ Wp, const float* __restrict__ W1,
          const float* __restrict__ bias, u16* __restrict__ Hh, u16* __restrict__ Hl,
          const float* __restrict__ W4, const float* __restrict__ b4,
          float* __restrict__ out, int nt)
{
  __shared__ __align__(16) u16 Sb[65536];   // 128 KB pool: A@{0,32K}, B@{64K,96K}

  const int tid  = threadIdx.x;
  const int lane = tid & 63;
  const int wv   = tid >> 6;            // 0..7
  const int wm   = wv >> 2, wn = wv & 3;

  int bid = blockIdx.x;
  bid = (bid & 7)*(NBG/8) + (bid >> 3);   // XCD-chunked swizzle (256%8==0)
  const int pxb = bid * BPXG;
  const int y   = bid;

  // hoisted staging-address invariants
  const int alane  = (lane & 15);
  const int akoff  = (lane >> 4)*8;
  const size_t abase0 = MODE == 0
      ? ((size_t)(y*SPAD + wv*32 + alane)*128 + akoff)
      : ((size_t)(pxb + wv*32 + alane)*HID + akoff);
  const size_t abaseStride = MODE == 0 ? (size_t)16*128 : (size_t)16*HID;

  f32x4 acc[8][4];
  #pragma unroll
  for (int a=0;a<8;a++)
    #pragma unroll
    for (int bq=0;bq<4;bq++) acc[a][bq] = f32x4{0.f,0.f,0.f,0.f};

#define A_STAGE(S, BUF) do { \
    size_t soff; \
    if (MODE == 0){ \
      const int tap = (S) >> 2, cg = (S) & 3; \
      soff = abase0 + (size_t)TAPOFF25[tap]*128 + cg*32; \
    } else { \
      soff = abase0 + (size_t)(S)*32; \
    } \
    _Pragma("unroll") \
    for (int u=0;u<2;++u){ \
      const int mfb = wv*2 + u; \
      const size_t off = soff + (size_t)u*abaseStride; \
      __builtin_amdgcn_global_load_lds( \
        (const __attribute__((address_space(1))) uint32_t*)(Ah + off), \
        (__attribute__((address_space(3))) uint32_t*)((char*)Sb + (size_t)(BUF)*32768 + (mfb*2+0)*1024), \
        16, 0, 0); \
      __builtin_amdgcn_global_load_lds( \
        (const __attribute__((address_space(1))) uint32_t*)(Al + off), \
        (__attribute__((address_space(3))) uint32_t*)((char*)Sb + (size_t)(BUF)*32768 + (mfb*2+1)*1024), \
        16, 0, 0); \
    } \
  } while(0)

#define B_STAGE(S, BUF) do { \
    const char* _src = (const char*)Wp + (size_t)(S)*32768 + wv*4096 + lane*16; \
    char* _dst = (char*)Sb + 65536 + (size_t)(BUF)*32768 + wv*4096; \
    _Pragma("unroll") \
    for (int i=0;i<4;++i) \
      __builtin_amdgcn_global_load_lds( \
        (const __attribute__((address_space(1))) uint32_t*)(_src + i*1024), \
        (__attribute__((address_space(3))) uint32_t*)(_dst + i*1024), 16, 0, 0); \
  } while(0)

  A_STAGE(0, 0); B_STAGE(0, 0);

  for (int t = 0; t < nt; ++t){
    asm volatile("s_waitcnt vmcnt(0)" ::: "memory");
    __builtin_amdgcn_s_barrier();
    __builtin_amdgcn_sched_barrier(0);
    const int cur = t & 1;

    const u16* Abuf = (const u16*)Sb + (size_t)cur*16384;
    const u16* Bbuf = (const u16*)Sb + 32768 + (size_t)cur*16384;

    // segment 1: B-frags + hf=0 A-frags (issue in barrier shadow)
    f16x8 bh[4], bl[4], a0h[4], a0l[4];
    #pragma unroll
    for (int nf=0;nf<4;++nf){
      bh[nf] = *(const f16x8*)(Bbuf + ((size_t)((wn*4+nf)*2+0)*64 + lane)*8);
      bl[nf] = *(const f16x8*)(Bbuf + ((size_t)((wn*4+nf)*2+1)*64 + lane)*8);
    }
    #pragma unroll
    for (int m=0;m<4;++m){
      const int mfb = wm*8 + m;
      a0h[m] = *(const f16x8*)(Abuf + ((size_t)(mfb*2+0)*64 + lane)*8);
      a0l[m] = *(const f16x8*)(Abuf + ((size_t)(mfb*2+1)*64 + lane)*8);
    }
    __builtin_amdgcn_sched_barrier(0);
    // segment 2: A staging issue (reads drain underneath)
    if (t+1 < nt) A_STAGE(t+1, cur^1);
    __builtin_amdgcn_sched_barrier(0);

    // segment 3: hf=0 pass-1 (a0h x bh)
    __builtin_amdgcn_s_setprio(1);
    #pragma unroll
    for (int m=0;m<4;++m)
      #pragma unroll
      for (int nf=0;nf<4;++nf)
        acc[m][nf] = __builtin_amdgcn_mfma_f32_16x16x32_f16(a0h[m], bh[nf], acc[m][nf], 0,0,0);
    __builtin_amdgcn_s_setprio(0);
    __builtin_amdgcn_sched_barrier(0);

    // segment 4: B staging issue + hf=1 hi A-frags (overlap MFMA drain)
    if (t+1 < nt) B_STAGE(t+1, cur^1);
    f16x8 a1h[4];
    #pragma unroll
    for (int m=0;m<4;++m){
      const int mfb = wm*8 + 4 + m;
      a1h[m] = *(const f16x8*)(Abuf + ((size_t)(mfb*2+0)*64 + lane)*8);
    }
    __builtin_amdgcn_sched_barrier(0);

    // segment 5: hf=0 pass-2 (a0l x bh) and pass-3 (a0h x bl)
    __builtin_amdgcn_s_setprio(1);
    #pragma unroll
    for (int m=0;m<4;++m)
      #pragma unroll
      for (int nf=0;nf<4;++nf)
        acc[m][nf] = __builtin_amdgcn_mfma_f32_16x16x32_f16(a0l[m], bh[nf], acc[m][nf], 0,0,0);
    #pragma unroll
    for (int m=0;m<4;++m)
      #pragma unroll
      for (int nf=0;nf<4;++nf)
        acc[m][nf] = __builtin_amdgcn_mfma_f32_16x16x32_f16(a0h[m], bl[nf], acc[m][nf], 0,0,0);
    __builtin_amdgcn_s_setprio(0);
    __builtin_amdgcn_sched_barrier(0);

    // segment 6: hf=1 lo A-frags (just-in-time; caps live frags)
    f16x8 a1l[4];
    #pragma unroll
    for (int m=0;m<4;++m){
      const int mfb = wm*8 + 4 + m;
      a1l[m] = *(const f16x8*)(Abuf + ((size_t)(mfb*2+1)*64 + lane)*8);
    }
    __builtin_amdgcn_sched_barrier(0);

    // segment 7: hf=1 passes (a1h x bh, a1l x bh, a1h x bl)
    __builtin_amdgcn_s_setprio(1);
    #pragma unroll
    for (int m=0;m<4;++m)
      #pragma unroll
      for (int nf=0;nf<4;++nf)
        acc[4+m][nf] = __builtin_amdgcn_mfma_f32_16x16x32_f16(a1h[m], bh[nf], acc[4+m][nf], 0,0,0);
    #pragma unroll
    for (int m=0;m<4;++m)
      #pragma unroll
      for (int nf=0;nf<4;++nf)
        acc[4+m][nf] = __builtin_amdgcn_mfma_f32_16x16x32_f16(a1l[m], bh[nf], acc[4+m][nf], 0,0,0);
    #pragma unroll
    for (int m=0;m<4;++m)
      #pragma unroll
      for (int nf=0;nf<4;++nf)
        acc[4+m][nf] = __builtin_amdgcn_mfma_f32_16x16x32_f16(a1h[m], bl[nf], acc[4+m][nf], 0,0,0);
    __builtin_amdgcn_s_setprio(0);
  }

  __syncthreads();   // loop LDS dead; MODE 2 overlays Sb

  float bcol[4];
  #pragma unroll
  for (int nf=0;nf<4;++nf) bcol[nf] = bias[wn*64 + nf*16 + (lane&15)];

  if (MODE == 0){
    float wyv[4], wxv[4];
    #pragma unroll
    for (int nf=0;nf<4;++nf){
      int col = wn*64 + nf*16 + (lane&15);
      wyv[nf] = W1[(size_t)3200*HID + col];
      wxv[nf] = W1[(size_t)3201*HID + col];
    }
    const float gy = -1.f + (2.f/255.f)*(float)y;
    #pragma unroll
    for (int mf=0;mf<8;++mf)
      #pragma unroll
      for (int nf=0;nf<4;++nf)
        #pragma unroll
        for (int j=0;j<4;++j){
          int row = wm*128 + mf*16 + (lane>>4)*4 + j;          // 0..255 = x coord
          float gx = -1.f + (2.f/255.f)*(float)row;
          float z = acc[mf][nf][j] + bcol[nf] + gy*wyv[nf] + gx*wxv[nf];
          float h = sinf(30.f*z);
          u16 hh,ll; split2(h,hh,ll);
          int col = wn*64 + nf*16 + (lane&15);
          size_t o = (size_t)(pxb+row)*HID + col;
          Hh[o] = hh; Hl[o] = ll;
        }
  } else if (MODE == 1){
    #pragma unroll
    for (int mf=0;mf<8;++mf)
      #pragma unroll
      for (int nf=0;nf<4;++nf)
        #pragma unroll
        for (int j=0;j<4;++j){
          float z = acc[mf][nf][j] + bcol[nf];
          float h = sinf(30.f*z);
          u16 hh,ll; split2(h,hh,ll);
          int row = wm*128 + mf*16 + (lane>>4)*4 + j;
          int col = wn*64 + nf*16 + (lane&15);
          size_t o = (size_t)(pxb+row)*HID + col;
          Hh[o] = hh; Hl[o] = ll;
        }
  } else {
    float (*red)[BPXG][3] = (float(*)[BPXG][3])(void*)Sb;  // 24 KB overlay, bufs dead
    float w4v[4][3];
    #pragma unroll
    for (int nf=0;nf<4;++nf){
      int col = wn*64 + nf*16 + (lane&15);
      w4v[nf][0]=W4[col*3+0]; w4v[nf][1]=W4[col*3+1]; w4v[nf][2]=W4[col*3+2];
    }
    #pragma unroll
    for (int mf=0;mf<8;++mf)
      #pragma unroll
      for (int j=0;j<4;++j){
        float s0=0.f,s1=0.f,s2=0.f;
        #pragma unroll
        for (int nf=0;nf<4;++nf){
          float h = sinf(30.f*(acc[mf][nf][j] + bcol[nf]));
          s0 += h*w4v[nf][0]; s1 += h*w4v[nf][1]; s2 += h*w4v[nf][2];
        }
        #pragma unroll
        for (int m=1;m<16;m<<=1){
          s0 += __shfl_xor(s0, m);
          s1 += __shfl_xor(s1, m);
          s2 += __shfl_xor(s2, m);
        }
        if ((lane & 15) == 0){
          int row = wm*128 + mf*16 + (lane>>4)*4 + j;
          red[wn + wm*4][row][0]=s0; red[wn + wm*4][row][1]=s1; red[wn + wm*4][row][2]=s2;
        }
      }
    __syncthreads();
    for (int o = tid; o < BPXG*3; o += 512){
      int px = o & 255, c = o >> 8;
      int wb = (px >> 7)*4;    // waves with wm = px>>7 hold this row
      float v = red[wb+0][px][c]+red[wb+1][px][c]+red[wb+2][px][c]+red[wb+3][px][c] + b4[c];
      out[(size_t)c*NPX + pxb + px] = v;
    }
  }
#undef A_STAGE
#undef B_STAGE
}

// ---------------------------------------------------------------------------
extern "C" void kernel_launch(void* const* d_in, const int* in_sizes, int n_in,
                              void* d_out, int out_size, void* d_ws, size_t ws_size,
                              hipStream_t stream) {
  const float* xi = (const float*)d_in[0];
  const float* W1 = (const float*)d_in[1];
  const float* b1 = (const float*)d_in[2];
  const float* W2 = (const float*)d_in[3];
  const float* b2 = (const float*)d_in[4];
  const float* W3 = (const float*)d_in[5];
  const float* b3 = (const float*)d_in[6];
  const float* W4 = (const float*)d_in[7];
  const float* b4 = (const float*)d_in[8];
  float* out = (float*)d_out;

  char* ws = (char*)d_ws;
  u16* W1c = (u16*)(ws + OFF_W1C);
  u16* W2p = (u16*)(ws + OFF_W2);
  u16* W3p = (u16*)(ws + OFF_W3);
  u16* Xh  = (u16*)(ws + OFF_XH);
  u16* Xl  = (u16*)(ws + OFF_XL);
  u16* Hh  = (u16*)(ws + OFF_HH);
  u16* Hl  = (u16*)(ws + OFF_HL);

  // 400 (W1 tap-major) + 32 (W2) + 32 (W3) + 265 (X planes) = 729 blocks
  prep_all<<<729, 256, 0, stream>>>(xi, W1, W2, W3, W1c, W2p, W3p, Xh, Xl);

  dim3 grid(NBG), block(512);
  gemm<0><<<grid, block, 0, stream>>>(Xh, Xl, W1c, W1, b1, Hh, Hl,
                                      nullptr, nullptr, nullptr, NS1C);
  gemm<1><<<grid, block, 0, stream>>>(Hh, Hl, W2p, nullptr, b2, Hh, Hl,
                                      nullptr, nullptr, nullptr, NS2);
  gemm<2><<<grid, block, 0, stream>>>(Hh, Hl, W3p, nullptr, b3, nullptr, nullptr,
                                      W4, b4, out, NS2);
}